// Round 1
// baseline (87.883 us; speedup 1.0000x reference)
//
#include <hip/hip_runtime.h>

#define D 64
#define H 8
#define LSEQ 2048
#define KMAX 64
#define NCODES 256   // 2^H

// ---------------------------------------------------------------------------
// Kernel 1: LSH codes for BOTH query and key positions.
// code = sum_h ( (sum_{d: x[d]>0} W[d][h]) > 0 ) << h
// Sequential over d (matches reference accumulation order — absmax has been
// exactly 0 every round; do not re-associate).
// BOTH query and key codes -> PERMUTED byte arrays laid out so the bucket
// kernel's uint load yields 4 ascending 64-chunks per lane:
//   byte for local pos (i*256 + j*64 + lane) lives at (i*256 + lane*4 + j).
// 64-thread blocks -> 256 blocks, one per CU.
// ---------------------------------------------------------------------------
__global__ void __launch_bounds__(64)
code_kernel(const float* __restrict__ query,
            const float* __restrict__ key,
            const float* __restrict__ W,
            unsigned char* __restrict__ qperm,   // [n_pos] permuted bytes
            unsigned char* __restrict__ kperm,   // [n_pos] permuted bytes
            int n_pos) {
    __shared__ float Ws[D * H];
    for (int i = threadIdx.x; i < D * H; i += blockDim.x) Ws[i] = W[i];
    __syncthreads();

    int t = blockIdx.x * blockDim.x + threadIdx.x;
    if (t >= 2 * n_pos) return;

    const float* xp = (t < n_pos) ? (query + (size_t)t * D)
                                  : (key + (size_t)(t - n_pos) * D);
    float4 s0 = {0.f, 0.f, 0.f, 0.f};
    float4 s1 = {0.f, 0.f, 0.f, 0.f};

    for (int d4 = 0; d4 < D / 4; ++d4) {
        float4 xv = ((const float4*)xp)[d4];
        const float* x4 = (const float*)&xv;
#pragma unroll
        for (int k = 0; k < 4; ++k) {
            if (x4[k] > 0.0f) {
                int d = d4 * 4 + k;
                float4 w0 = *(const float4*)&Ws[d * H + 0];   // LDS broadcast
                float4 w1 = *(const float4*)&Ws[d * H + 4];
                s0.x += w0.x; s0.y += w0.y; s0.z += w0.z; s0.w += w0.w;
                s1.x += w1.x; s1.y += w1.y; s1.z += w1.z; s1.w += w1.w;
            }
        }
    }
    int c = 0;
    c |= (s0.x > 0.0f) ? 1   : 0;
    c |= (s0.y > 0.0f) ? 2   : 0;
    c |= (s0.z > 0.0f) ? 4   : 0;
    c |= (s0.w > 0.0f) ? 8   : 0;
    c |= (s1.x > 0.0f) ? 16  : 0;
    c |= (s1.y > 0.0f) ? 32  : 0;
    c |= (s1.z > 0.0f) ? 64  : 0;
    c |= (s1.w > 0.0f) ? 128 : 0;

    int p = (t < n_pos) ? t : t - n_pos;
    unsigned char* dst = (t < n_pos) ? qperm : kperm;
    int b    = p >> 11;             // LSEQ = 2048
    int l    = p & (LSEQ - 1);
    int lane = l & 63;
    int j    = (l >> 6) & 3;
    int i4   = l >> 8;
    dst[(b << 11) + (i4 << 8) + (lane << 2) + j] = (unsigned char)c;
}

// ---------------------------------------------------------------------------
// Kernel 2 (bucket build + emit): there are only B*NCODES = 1024 DISTINCT
// output rows (a query's row depends only on (batch, q_code)). One WAVE per
// (batch, code): build the bucket row once with the verified ballot-rank
// scan over the key codes (8x fewer waves than one-wave-per-query), then
// ballot-scan the QUERY codes and broadcast-store the finished 256B row to
// every matching query. Each query's code matches exactly one (b,c) wave,
// so every output row is written exactly once — no pre-fill, no races.
// ---------------------------------------------------------------------------
__global__ void __launch_bounds__(256)
bucket_emit_kernel(const unsigned int* __restrict__ qperm,  // [B][LSEQ/4]
                   const unsigned int* __restrict__ kperm,  // [B][LSEQ/4]
                   int* __restrict__ out) {                  // [B*LSEQ][KMAX]
    __shared__ int rows[4][KMAX];
    int wave = threadIdx.x >> 6;
    int lane = threadIdx.x & 63;
    int wid  = blockIdx.x * 4 + wave;      // 0..1023 = (batch, code)
    int b = wid >> 8;
    int c = wid & (NCODES - 1);

    const unsigned int* kp = kperm + (size_t)b * (LSEQ / 4) + lane;
    const unsigned int* qp = qperm + (size_t)b * (LSEQ / 4) + lane;

    int* row = rows[wave];
    row[lane] = -1;

    unsigned int kv[LSEQ / 256];           // 8 uints = 32 key codes per lane
    unsigned int qv[LSEQ / 256];           // 8 uints = 32 query codes per lane
#pragma unroll
    for (int i = 0; i < LSEQ / 256; ++i) kv[i] = kp[i * 64];  // all in flight
#pragma unroll
    for (int i = 0; i < LSEQ / 256; ++i) qv[i] = qp[i * 64];

    unsigned long long lt_mask = (lane == 63) ? 0x7FFFFFFFFFFFFFFFull
                                              : ((1ull << lane) - 1ull);
    // ---- build: rank first <=KMAX ascending key matches into the row ----
    int base = 0;
#pragma unroll
    for (int i = 0; i < LSEQ / 256; ++i) {
        unsigned int w = kv[i];
#pragma unroll
        for (int j = 0; j < 4; ++j) {
            int ci = (int)((w >> (8 * j)) & 0xFFu);
            unsigned long long mask = __ballot(ci == c);
            if (ci == c) {
                int rank = base + __popcll(mask & lt_mask);
                if (rank < KMAX) row[rank] = i * 256 + j * 64 + lane;
            }
            base += __popcll(mask);
        }
    }
    int myrow = row[lane];                 // wave-private LDS, program order

    // ---- emit: store the row to every query whose code == c ----
    long long out_base = (long long)b * LSEQ * KMAX;
#pragma unroll
    for (int i = 0; i < LSEQ / 256; ++i) {
        unsigned int w = qv[i];
#pragma unroll
        for (int j = 0; j < 4; ++j) {
            int ci = (int)((w >> (8 * j)) & 0xFFu);
            unsigned long long m = __ballot(ci == c);   // uniform mask
            while (m) {                                  // ~8 hits/wave total
                int s = __builtin_ctzll(m);
                m &= m - 1;
                int ql = i * 256 + j * 64 + s;
                out[out_base + (long long)ql * KMAX + lane] = myrow;  // 256B
            }
        }
    }
}

extern "C" void kernel_launch(void* const* d_in, const int* in_sizes, int n_in,
                              void* d_out, int out_size, void* d_ws, size_t ws_size,
                              hipStream_t stream) {
    const float* query = (const float*)d_in[0];
    const float* key   = (const float*)d_in[1];
    const float* W     = (const float*)d_in[2];
    // d_in[3] = head_idx (unused)

    int n_pos = in_sizes[0] / D;        // B*L = 8192
    (void)ws_size;

    unsigned char* kperm = (unsigned char*)d_ws;       // n_pos bytes
    unsigned char* qperm = kperm + n_pos;              // n_pos bytes (4B-aligned)

    {
        int total = 2 * n_pos;          // 16384 positions, 64-thread blocks
        code_kernel<<<(total + 63) / 64, 64, 0, stream>>>(query, key, W,
                                                          qperm, kperm, n_pos);
    }
    {
        // one wave per (batch, code): 4*256 = 1024 waves, 4 waves per block
        bucket_emit_kernel<<<(4 * NCODES) / 4, 256, 0, stream>>>(
            (const unsigned int*)qperm, (const unsigned int*)kperm, (int*)d_out);
    }
}

// Round 2
// 72.810 us; speedup vs baseline: 1.2070x; 1.2070x over previous
//
#include <hip/hip_runtime.h>

#define D 64
#define H 8
#define LSEQ 2048
#define KMAX 64
#define NCODES 256   // 2^H

// ---------------------------------------------------------------------------
// Kernel 1: LSH codes for BOTH query and key positions.
// code = sum_h ( (sum_{d: x[d]>0} W[d][h]) > 0 ) << h
// Sequential over d (matches reference accumulation order — absmax has been
// exactly 0 every round; do not re-associate).
// BRANCHLESS accumulation: s += (x>0) ? w : 0.0f. Bit-identical to the
// branchy form (partial sums are never -0.0, so +0.0 adds are exact no-ops)
// but the ds_reads become unconditional wave-uniform broadcasts the compiler
// can hoist/pipeline instead of exec-mask-guarded serialized loads.
// Query codes -> int array. Key codes -> PERMUTED byte array laid out so the
// scan kernel's uint load yields 4 ascending 64-chunks per lane:
//   byte for local pos (i*256 + j*64 + lane) lives at (i*256 + lane*4 + j).
// 64-thread blocks -> 256 blocks, one per CU.
// ---------------------------------------------------------------------------
__global__ void __launch_bounds__(64)
code_kernel(const float* __restrict__ query,
            const float* __restrict__ key,
            const float* __restrict__ W,
            int* __restrict__ q_code,            // [n_pos]
            unsigned char* __restrict__ kperm,   // [n_pos] permuted bytes
            int n_pos) {
    __shared__ float Ws[D * H];
    for (int i = threadIdx.x; i < D * H; i += blockDim.x) Ws[i] = W[i];
    __syncthreads();

    int t = blockIdx.x * blockDim.x + threadIdx.x;
    if (t >= 2 * n_pos) return;

    const float* xp = (t < n_pos) ? (query + (size_t)t * D)
                                  : (key + (size_t)(t - n_pos) * D);
    float4 s0 = {0.f, 0.f, 0.f, 0.f};
    float4 s1 = {0.f, 0.f, 0.f, 0.f};

#pragma unroll
    for (int d4 = 0; d4 < D / 4; ++d4) {
        float4 xv = ((const float4*)xp)[d4];
        const float* x4 = (const float*)&xv;
#pragma unroll
        for (int k = 0; k < 4; ++k) {
            int d = d4 * 4 + k;
            float4 w0 = *(const float4*)&Ws[d * H + 0];   // LDS broadcast
            float4 w1 = *(const float4*)&Ws[d * H + 4];
            bool p = x4[k] > 0.0f;
            s0.x += p ? w0.x : 0.0f;
            s0.y += p ? w0.y : 0.0f;
            s0.z += p ? w0.z : 0.0f;
            s0.w += p ? w0.w : 0.0f;
            s1.x += p ? w1.x : 0.0f;
            s1.y += p ? w1.y : 0.0f;
            s1.z += p ? w1.z : 0.0f;
            s1.w += p ? w1.w : 0.0f;
        }
    }
    int c = 0;
    c |= (s0.x > 0.0f) ? 1   : 0;
    c |= (s0.y > 0.0f) ? 2   : 0;
    c |= (s0.z > 0.0f) ? 4   : 0;
    c |= (s0.w > 0.0f) ? 8   : 0;
    c |= (s1.x > 0.0f) ? 16  : 0;
    c |= (s1.y > 0.0f) ? 32  : 0;
    c |= (s1.z > 0.0f) ? 64  : 0;
    c |= (s1.w > 0.0f) ? 128 : 0;

    if (t < n_pos) {
        q_code[t] = c;
    } else {
        int kk = t - n_pos;
        int b    = kk >> 11;            // LSEQ = 2048
        int l    = kk & (LSEQ - 1);
        int lane = l & 63;
        int j    = (l >> 6) & 3;
        int i4   = l >> 8;
        kperm[(b << 11) + (i4 << 8) + (lane << 2) + j] = (unsigned char)c;
    }
}

// ---------------------------------------------------------------------------
// Kernel 2 (fused scan + emit): one WAVE per QUERY. All 8 code-uints are
// PRELOADED into registers (no early exit -> loads fully pipelined), then
// 32 ballot sub-steps rank the first <=KMAX ascending matches into a
// -1-padded LDS row, emitted as one coalesced 256B store.
// PROVEN structure (74 µs): 8192 waves = 8 waves/SIMD keeps TLP high; the
// round-1 dedup variant (1024 waves) lost 14 µs to exposed latency.
// ---------------------------------------------------------------------------
__global__ void __launch_bounds__(256)
scan_emit_kernel(const int* __restrict__ q_code,          // [B*LSEQ]
                 const unsigned int* __restrict__ kperm,  // [B][LSEQ/4]
                 int* __restrict__ out) {                 // [B*LSEQ][KMAX]
    __shared__ int rows[4][KMAX];
    int wave = threadIdx.x >> 6;
    int lane = threadIdx.x & 63;
    int q = blockIdx.x * 4 + wave;       // global query index
    int b = q >> 11;                     // LSEQ = 2048

    int c = q_code[q];                   // wave-uniform broadcast load
    const unsigned int* kp = kperm + (size_t)b * (LSEQ / 4) + lane;
    int* row = rows[wave];
    row[lane] = -1;

    unsigned int v[LSEQ / 256];          // 8 uints = 32 codes' worth per lane
#pragma unroll
    for (int i = 0; i < LSEQ / 256; ++i) v[i] = kp[i * 64];   // all in flight

    unsigned long long lt_mask = (lane == 63) ? 0x7FFFFFFFFFFFFFFFull
                                              : ((1ull << lane) - 1ull);
    int base = 0;
#pragma unroll
    for (int i = 0; i < LSEQ / 256; ++i) {
        unsigned int w = v[i];
#pragma unroll
        for (int j = 0; j < 4; ++j) {
            int ci = (int)((w >> (8 * j)) & 0xFFu);
            unsigned long long mask = __ballot(ci == c);
            if (ci == c) {
                int rank = base + __popcll(mask & lt_mask);
                if (rank < KMAX) row[rank] = i * 256 + j * 64 + lane;
            }
            base += __popcll(mask);
        }
    }
    out[(size_t)q * KMAX + lane] = row[lane];         // 256B coalesced
}

extern "C" void kernel_launch(void* const* d_in, const int* in_sizes, int n_in,
                              void* d_out, int out_size, void* d_ws, size_t ws_size,
                              hipStream_t stream) {
    const float* query = (const float*)d_in[0];
    const float* key   = (const float*)d_in[1];
    const float* W     = (const float*)d_in[2];
    // d_in[3] = head_idx (unused)

    int n_pos = in_sizes[0] / D;        // B*L = 8192
    (void)ws_size;

    int* q_code = (int*)d_ws;                         // n_pos ints (32 KB)
    unsigned char* kperm = (unsigned char*)(q_code + n_pos);  // n_pos bytes

    {
        int total = 2 * n_pos;          // 16384 positions, 64-thread blocks
        code_kernel<<<(total + 63) / 64, 64, 0, stream>>>(query, key, W,
                                                          q_code, kperm, n_pos);
    }
    {
        // one wave per query, 4 waves per block
        scan_emit_kernel<<<n_pos / 4, 256, 0, stream>>>(q_code,
                                                        (const unsigned int*)kperm,
                                                        (int*)d_out);
    }
}

// Round 3
// 71.005 us; speedup vs baseline: 1.2377x; 1.0254x over previous
//
#include <hip/hip_runtime.h>

#define D 64
#define H 8
#define LSEQ 2048
#define KMAX 64
#define NCODES 256   // 2^H

// ---------------------------------------------------------------------------
// Kernel 1: LSH codes for BOTH query and key positions.
// code = sum_h ( (sum_{d: x[d]>0} W[d][h]) > 0 ) << h
// Sequential over d (matches reference accumulation order — absmax has been
// exactly 0 every round; do not re-associate).
// BRANCHLESS accumulation: s += (x>0) ? w : 0.0f. Bit-identical to the
// branchy form (partial sums are never -0.0, so +0.0 adds are exact no-ops)
// but the ds_reads are unconditional wave-uniform broadcasts the compiler
// can hoist/pipeline instead of exec-mask-guarded serialized loads.
// Query codes -> int array. Key codes -> LINEAR byte array (the lane-segment
// scan layout makes the identity layout ideal: lane l of a scan wave owns
// positions [l*32, l*32+32) = bytes [l*32, l*32+32)).
// ---------------------------------------------------------------------------
__global__ void __launch_bounds__(64)
code_kernel(const float* __restrict__ query,
            const float* __restrict__ key,
            const float* __restrict__ W,
            int* __restrict__ q_code,            // [n_pos]
            unsigned char* __restrict__ kcode,   // [n_pos] linear bytes
            int n_pos) {
    __shared__ float Ws[D * H];
    for (int i = threadIdx.x; i < D * H; i += blockDim.x) Ws[i] = W[i];
    __syncthreads();

    int t = blockIdx.x * blockDim.x + threadIdx.x;
    if (t >= 2 * n_pos) return;

    const float* xp = (t < n_pos) ? (query + (size_t)t * D)
                                  : (key + (size_t)(t - n_pos) * D);
    float4 s0 = {0.f, 0.f, 0.f, 0.f};
    float4 s1 = {0.f, 0.f, 0.f, 0.f};

#pragma unroll
    for (int d4 = 0; d4 < D / 4; ++d4) {
        float4 xv = ((const float4*)xp)[d4];
        const float* x4 = (const float*)&xv;
#pragma unroll
        for (int k = 0; k < 4; ++k) {
            int d = d4 * 4 + k;
            float4 w0 = *(const float4*)&Ws[d * H + 0];   // LDS broadcast
            float4 w1 = *(const float4*)&Ws[d * H + 4];
            bool p = x4[k] > 0.0f;
            s0.x += p ? w0.x : 0.0f;
            s0.y += p ? w0.y : 0.0f;
            s0.z += p ? w0.z : 0.0f;
            s0.w += p ? w0.w : 0.0f;
            s1.x += p ? w1.x : 0.0f;
            s1.y += p ? w1.y : 0.0f;
            s1.z += p ? w1.z : 0.0f;
            s1.w += p ? w1.w : 0.0f;
        }
    }
    int c = 0;
    c |= (s0.x > 0.0f) ? 1   : 0;
    c |= (s0.y > 0.0f) ? 2   : 0;
    c |= (s0.z > 0.0f) ? 4   : 0;
    c |= (s0.w > 0.0f) ? 8   : 0;
    c |= (s1.x > 0.0f) ? 16  : 0;
    c |= (s1.y > 0.0f) ? 32  : 0;
    c |= (s1.z > 0.0f) ? 64  : 0;
    c |= (s1.w > 0.0f) ? 128 : 0;

    if (t < n_pos) {
        q_code[t] = c;
    } else {
        kcode[t - n_pos] = (unsigned char)c;   // linear: byte p = position p
    }
}

// ---------------------------------------------------------------------------
// Kernel 2 (lane-segment scan + emit): one WAVE per QUERY, 8 waves/SIMD.
// Lane l owns key positions [l*32, l*32+32) of its batch (32 contiguous
// bytes, loaded as 2x uint4 -> wave reads 2048B fully coalesced).
//  1) build a private 32-bit match mask  (independent VALU, no cross-lane)
//  2) cnt = popc(mask); 6-step shfl_up prefix sum -> per-lane output base
//  3) scatter matched indices (ascending in-lane, ascending across lanes
//     -> globally ascending; ranks disjoint by prefix sum) into the -1
//     prefilled LDS row; clip at KMAX.
// Replaces the previous 32 sequential ballot rounds (per-round scalar
// dependency chain) with ~150 independent VALU + one depth-6 scan.
// ---------------------------------------------------------------------------
__global__ void __launch_bounds__(256)
scan_emit_kernel(const int* __restrict__ q_code,          // [B*LSEQ]
                 const unsigned char* __restrict__ kcode, // [B][LSEQ]
                 int* __restrict__ out) {                 // [B*LSEQ][KMAX]
    __shared__ int rows[4][KMAX];
    int wave = threadIdx.x >> 6;
    int lane = threadIdx.x & 63;
    int q = blockIdx.x * 4 + wave;       // global query index
    int b = q >> 11;                     // LSEQ = 2048

    unsigned int cu = (unsigned int)q_code[q];     // wave-uniform broadcast
    const uint4* kp4 = (const uint4*)(kcode + (size_t)b * LSEQ) + lane * 2;
    int* row = rows[wave];
    row[lane] = -1;

    uint4 v0 = kp4[0];                   // 32 consecutive key codes per lane
    uint4 v1 = kp4[1];

    // ---- pass 1: private match mask over the lane's 32 bytes ----
    unsigned int m = 0;
    {
        const unsigned int* w0 = (const unsigned int*)&v0;
        const unsigned int* w1 = (const unsigned int*)&v1;
#pragma unroll
        for (int u = 0; u < 4; ++u) {
            unsigned int w = w0[u];
#pragma unroll
            for (int j = 0; j < 4; ++j)
                if (((w >> (8 * j)) & 0xFFu) == cu) m |= 1u << (u * 4 + j);
        }
#pragma unroll
        for (int u = 0; u < 4; ++u) {
            unsigned int w = w1[u];
#pragma unroll
            for (int j = 0; j < 4; ++j)
                if (((w >> (8 * j)) & 0xFFu) == cu) m |= 1u << (16 + u * 4 + j);
        }
    }
    int cnt = __popc(m);

    // ---- prefix sum over lanes (inclusive scan, 6 steps) ----
    int inc = cnt;
#pragma unroll
    for (int d = 1; d < 64; d <<= 1) {
        int n = __shfl_up(inc, d);
        if (lane >= d) inc += n;
    }
    int base = inc - cnt;                // exclusive prefix = my output base

    // ---- pass 2: scatter matched indices (avg ~8 matches per WAVE) ----
    unsigned int mm = m;
    int k = 0;
    while (mm) {
        int tz = __builtin_ctz(mm);
        mm &= mm - 1;
        int r = base + k;
        if (r < KMAX) row[r] = lane * 32 + tz;
        ++k;
    }

    out[(size_t)q * KMAX + lane] = row[lane];      // 256B coalesced
}

extern "C" void kernel_launch(void* const* d_in, const int* in_sizes, int n_in,
                              void* d_out, int out_size, void* d_ws, size_t ws_size,
                              hipStream_t stream) {
    const float* query = (const float*)d_in[0];
    const float* key   = (const float*)d_in[1];
    const float* W     = (const float*)d_in[2];
    // d_in[3] = head_idx (unused)

    int n_pos = in_sizes[0] / D;        // B*L = 8192
    (void)ws_size;

    int* q_code = (int*)d_ws;                          // n_pos ints (32 KB)
    unsigned char* kcode = (unsigned char*)(q_code + n_pos);  // n_pos bytes

    {
        int total = 2 * n_pos;          // 16384 positions, 64-thread blocks
        code_kernel<<<(total + 63) / 64, 64, 0, stream>>>(query, key, W,
                                                          q_code, kcode, n_pos);
    }
    {
        // one wave per query, 4 waves per block
        scan_emit_kernel<<<n_pos / 4, 256, 0, stream>>>(q_code, kcode,
                                                        (int*)d_out);
    }
}

// Round 4
// 69.877 us; speedup vs baseline: 1.2577x; 1.0161x over previous
//
#include <hip/hip_runtime.h>

#define D 64
#define H 8
#define LSEQ 2048
#define KMAX 64
#define NCODES 256   // 2^H

// ---------------------------------------------------------------------------
// Kernel 1: LSH codes for BOTH query and key positions.
// code = sum_h ( (sum_{d: x[d]>0} W[d][h]) > 0 ) << h
// Sequential over d (matches reference accumulation order — absmax has been
// exactly 0 every round; do not re-associate).
// PREDICATED-FMA accumulation: t = (x>0)?1:0; s = fma(t, w, s).
//   fma(1,w,s) = RN(w+s) == v_add_f32;  fma(0,w,s) = s (s is never -0.0:
//   it starts +0.0 and RN cancellation yields +0.0). Bit-identical to the
//   branchy original, but 10 insts/d instead of 17 (v_cmp + cndmask + 8 fmac
//   vs v_cmp + 8 cndmask + 8 add). Kernel runs at 1 wave/CU, so issue count
//   ~= runtime.
// Query codes -> int array. Key codes -> LINEAR byte array (lane-segment
// scan layout: lane l of a scan wave owns bytes [l*32, l*32+32)).
// ---------------------------------------------------------------------------
__global__ void __launch_bounds__(64)
code_kernel(const float* __restrict__ query,
            const float* __restrict__ key,
            const float* __restrict__ W,
            int* __restrict__ q_code,            // [n_pos]
            unsigned char* __restrict__ kcode,   // [n_pos] linear bytes
            int n_pos) {
    __shared__ float Ws[D * H];
    for (int i = threadIdx.x; i < D * H; i += blockDim.x) Ws[i] = W[i];
    __syncthreads();

    int t = blockIdx.x * blockDim.x + threadIdx.x;
    if (t >= 2 * n_pos) return;

    const float* xp = (t < n_pos) ? (query + (size_t)t * D)
                                  : (key + (size_t)(t - n_pos) * D);
    float4 s0 = {0.f, 0.f, 0.f, 0.f};
    float4 s1 = {0.f, 0.f, 0.f, 0.f};

#pragma unroll
    for (int d4 = 0; d4 < D / 4; ++d4) {
        float4 xv = ((const float4*)xp)[d4];
        const float* x4 = (const float*)&xv;
#pragma unroll
        for (int k = 0; k < 4; ++k) {
            int d = d4 * 4 + k;
            float4 w0 = *(const float4*)&Ws[d * H + 0];   // LDS broadcast
            float4 w1 = *(const float4*)&Ws[d * H + 4];
            float p = (x4[k] > 0.0f) ? 1.0f : 0.0f;
            s0.x = __builtin_fmaf(p, w0.x, s0.x);
            s0.y = __builtin_fmaf(p, w0.y, s0.y);
            s0.z = __builtin_fmaf(p, w0.z, s0.z);
            s0.w = __builtin_fmaf(p, w0.w, s0.w);
            s1.x = __builtin_fmaf(p, w1.x, s1.x);
            s1.y = __builtin_fmaf(p, w1.y, s1.y);
            s1.z = __builtin_fmaf(p, w1.z, s1.z);
            s1.w = __builtin_fmaf(p, w1.w, s1.w);
        }
    }
    int c = 0;
    c |= (s0.x > 0.0f) ? 1   : 0;
    c |= (s0.y > 0.0f) ? 2   : 0;
    c |= (s0.z > 0.0f) ? 4   : 0;
    c |= (s0.w > 0.0f) ? 8   : 0;
    c |= (s1.x > 0.0f) ? 16  : 0;
    c |= (s1.y > 0.0f) ? 32  : 0;
    c |= (s1.z > 0.0f) ? 64  : 0;
    c |= (s1.w > 0.0f) ? 128 : 0;

    if (t < n_pos) {
        q_code[t] = c;
    } else {
        kcode[t - n_pos] = (unsigned char)c;   // linear: byte p = position p
    }
}

// ---------------------------------------------------------------------------
// Kernel 2 (lane-segment scan + emit): one WAVE per QUERY, 8 waves/SIMD.
// PROVEN structure (71.0 µs) — unchanged this round.
// Lane l owns key positions [l*32, l*32+32) of its batch (32 contiguous
// bytes, loaded as 2x uint4 -> wave reads 2048B fully coalesced).
//  1) build a private 32-bit match mask  (independent VALU, no cross-lane)
//  2) cnt = popc(mask); 6-step shfl_up prefix sum -> per-lane output base
//  3) scatter matched indices (ascending in-lane, ascending across lanes
//     -> globally ascending; ranks disjoint by prefix sum) into the -1
//     prefilled LDS row; clip at KMAX.
// ---------------------------------------------------------------------------
__global__ void __launch_bounds__(256)
scan_emit_kernel(const int* __restrict__ q_code,          // [B*LSEQ]
                 const unsigned char* __restrict__ kcode, // [B][LSEQ]
                 int* __restrict__ out) {                 // [B*LSEQ][KMAX]
    __shared__ int rows[4][KMAX];
    int wave = threadIdx.x >> 6;
    int lane = threadIdx.x & 63;
    int q = blockIdx.x * 4 + wave;       // global query index
    int b = q >> 11;                     // LSEQ = 2048

    unsigned int cu = (unsigned int)q_code[q];     // wave-uniform broadcast
    const uint4* kp4 = (const uint4*)(kcode + (size_t)b * LSEQ) + lane * 2;
    int* row = rows[wave];
    row[lane] = -1;

    uint4 v0 = kp4[0];                   // 32 consecutive key codes per lane
    uint4 v1 = kp4[1];

    // ---- pass 1: private match mask over the lane's 32 bytes ----
    unsigned int m = 0;
    {
        const unsigned int* w0 = (const unsigned int*)&v0;
        const unsigned int* w1 = (const unsigned int*)&v1;
#pragma unroll
        for (int u = 0; u < 4; ++u) {
            unsigned int w = w0[u];
#pragma unroll
            for (int j = 0; j < 4; ++j)
                if (((w >> (8 * j)) & 0xFFu) == cu) m |= 1u << (u * 4 + j);
        }
#pragma unroll
        for (int u = 0; u < 4; ++u) {
            unsigned int w = w1[u];
#pragma unroll
            for (int j = 0; j < 4; ++j)
                if (((w >> (8 * j)) & 0xFFu) == cu) m |= 1u << (16 + u * 4 + j);
        }
    }
    int cnt = __popc(m);

    // ---- prefix sum over lanes (inclusive scan, 6 steps) ----
    int inc = cnt;
#pragma unroll
    for (int d = 1; d < 64; d <<= 1) {
        int n = __shfl_up(inc, d);
        if (lane >= d) inc += n;
    }
    int base = inc - cnt;                // exclusive prefix = my output base

    // ---- pass 2: scatter matched indices (avg ~8 matches per WAVE) ----
    unsigned int mm = m;
    int k = 0;
    while (mm) {
        int tz = __builtin_ctz(mm);
        mm &= mm - 1;
        int r = base + k;
        if (r < KMAX) row[r] = lane * 32 + tz;
        ++k;
    }

    out[(size_t)q * KMAX + lane] = row[lane];      // 256B coalesced
}

extern "C" void kernel_launch(void* const* d_in, const int* in_sizes, int n_in,
                              void* d_out, int out_size, void* d_ws, size_t ws_size,
                              hipStream_t stream) {
    const float* query = (const float*)d_in[0];
    const float* key   = (const float*)d_in[1];
    const float* W     = (const float*)d_in[2];
    // d_in[3] = head_idx (unused)

    int n_pos = in_sizes[0] / D;        // B*L = 8192
    (void)ws_size;

    int* q_code = (int*)d_ws;                          // n_pos ints (32 KB)
    unsigned char* kcode = (unsigned char*)(q_code + n_pos);  // n_pos bytes

    {
        int total = 2 * n_pos;          // 16384 positions, 64-thread blocks
        code_kernel<<<(total + 63) / 64, 64, 0, stream>>>(query, key, W,
                                                          q_code, kcode, n_pos);
    }
    {
        // one wave per query, 4 waves per block
        scan_emit_kernel<<<n_pos / 4, 256, 0, stream>>>(q_code, kcode,
                                                        (int*)d_out);
    }
}